// Round 5
// baseline (148.654 us; speedup 1.0000x reference)
//
#include <hip/hip_runtime.h>
#include <hip/hip_bf16.h>
#include <math.h>

// B=4, N=2048, C=320, H=5, D=64, INNER=320, BH=20
// logit = (q*0.125*log2e*e_i) . (k*e_j); softmax via exp2 (bounded, no max).
// e_bh = edge[(b+h)%4]  (batch-minor edge tiling vs batch-major heads)
//
// Fragment-major layouts (every main-loop load = lane-contiguous b128):
//  xb  tiles (mt2=m/16, kc=k/32): elem (qq*16+mm)*8+e  = x[m][k], qq=(k%32)>>3
//  wt  tiles (z, nt2=n/16, kc):   elem (qq*16+nn)*8+e  = W[k][n]
//  kS  [bh][j/16][d/32][slot]:    slot ((d>>3)&3)*16+(j&15), e=d&7
//  vS  [bh][d/16][j/64][kb][slot]: PV mfma32 A-frag order (see r3 notes)
//  ao  tiles like xb (A-operand of oproj)
//  qp  row-major [bh][n][64]
//
// r16 == r15 resubmitted verbatim (round-4 bench was an infra failure:
// "container failed twice", no counters; source re-audited for OOB/hang —
// grid decode bijective, LDS max 16376<16384 incl lane*16, stage reads in
// [bh*131072,+131072), same barrier structure as the passing r14).
//
// r15: QBLK=128. r14 post-mortem: attn (~36us inferred) was LDS-pipe bound:
// 640 blocks x 2MB ds_read_b128 + 0.5MB stage-writes ~= 29-32us/CU of LDS
// issue. K/V fragments are q-independent, so each wave now owns TWO 16-q
// tiles: same 8 b128 reads per uu feed 2x MFMA -> chip LDS reads halve
// (640->320MB), L2 K/V traffic halves (336->168MB). ~105 VGPR fits the
// 128 cap of (256,4). Grid 320 (16 qg x 20 bh); 64 CUs get 2 blocks ->
// wall ~2x single-block (~20-22us). Ledger: 2 poison fills ~83us +
// prep/qkv/oproj ~9us are the fixed floor; attn is the only lever.

typedef short bf16x8 __attribute__((ext_vector_type(8)));
typedef float f32x4 __attribute__((ext_vector_type(4)));

static __device__ __forceinline__ ushort f2bf(float f) {
  union { float f; unsigned u; } v; v.f = f;
  unsigned r = (v.u + 0x7fffu + ((v.u >> 16) & 1u)) >> 16;
  return (ushort)r;
}
static __device__ __forceinline__ float fexp2(float x) {
#if __has_builtin(__builtin_amdgcn_exp2f)
  return __builtin_amdgcn_exp2f(x);
#else
  return exp2f(x);
#endif
}
static __device__ __forceinline__ f32x4 mfma32(bf16x8 a, bf16x8 b, f32x4 c) {
  return __builtin_amdgcn_mfma_f32_16x16x32_bf16(a, b, c, 0, 0, 0);
}

#define GLD_LDS16(gsrc, ldst)                                                  \
  __builtin_amdgcn_global_load_lds(                                            \
      (const __attribute__((address_space(1))) unsigned int*)(gsrc),           \
      (__attribute__((address_space(3))) unsigned int*)(ldst), 16, 0, 0)

// ---------------------------------------------------------------------------
// Prep (fused): flat grid 3360. (verbatim r9)
// ---------------------------------------------------------------------------
__global__ __launch_bounds__(256) void prep_kernel(
    const float* __restrict__ x,
    const float* __restrict__ Wq, const float* __restrict__ Wk,
    const float* __restrict__ Wv, const float* __restrict__ Wo,
    ushort* __restrict__ xb, ushort* __restrict__ wt)
{
  const int w = blockIdx.x;
  if (w < 2560) {
    const int t = threadIdx.x;
    const int mt2 = w / 5;
    const int kc = (w % 5) * 2 + (t >> 7);
    const int f = (t & 127) * 4;
    const int qq = f >> 7, mm = (f >> 3) & 15, e0 = f & 7;
    float4 v = *reinterpret_cast<const float4*>(
        x + (size_t)(mt2 * 16 + mm) * 320 + kc * 32 + qq * 8 + e0);
    ushort4 o = { f2bf(v.x), f2bf(v.y), f2bf(v.z), f2bf(v.w) };
    *reinterpret_cast<ushort4*>(xb + (size_t)(mt2 * 10 + kc) * 512 + f) = o;
  } else {
    const int w2 = w - 2560;
    const int nt2 = w2 % 20, kc = (w2 / 20) % 10, z = w2 / 200;
    const float* W = z == 0 ? Wq : z == 1 ? Wk : z == 2 ? Wv : Wo;
    const int f = threadIdx.x * 2;
    const int qq = f >> 7, nn = (f >> 3) & 15, e0 = f & 7;
    const int k = kc * 32 + qq * 8 + e0, n = nt2 * 16 + nn;
    float v0 = W[(size_t)k * 320 + n];
    float v1 = W[(size_t)(k + 1) * 320 + n];
    ushort2 o = { f2bf(v0), f2bf(v1) };
    *reinterpret_cast<ushort2*>(
        wt + (size_t)z * 102400 + (size_t)(nt2 * 10 + kc) * 512 + f) = o;
  }
}

// ---------------------------------------------------------------------------
// Kernel 1: QKV projection big-tile (verbatim r9).
// ---------------------------------------------------------------------------
__global__ __launch_bounds__(256, 3) void qkv_gemm(
    const ushort* __restrict__ xb, const float* __restrict__ edge,
    const ushort* __restrict__ wt,
    ushort* __restrict__ qp, ushort* __restrict__ kS, ushort* __restrict__ vS)
{
  const int w = blockIdx.x;
  const int s = (w & 7) * 60 + (w >> 3);
  const int mg = s / 15, zh = s % 15;
  const int z = zh / 5, h = zh % 5;
  const int wave = threadIdx.x >> 6, lane = threadIdx.x & 63;
  const int m16 = lane & 15, quad = lane >> 4;
  const int m0 = mg * 256 + wave * 64;
  const ushort* atile = xb + (size_t)(m0 >> 4) * 5120 + lane * 8;
  const ushort* btile = wt + (size_t)z * 102400 + (size_t)(h * 4) * 5120 + lane * 8;

  f32x4 acc[4][4];
#pragma unroll
  for (int i = 0; i < 4; ++i)
#pragma unroll
    for (int ns = 0; ns < 4; ++ns) acc[i][ns] = (f32x4){0.f, 0.f, 0.f, 0.f};

#pragma unroll
  for (int kc = 0; kc < 10; ++kc) {
    bf16x8 af[4], bf[4];
#pragma unroll
    for (int i = 0; i < 4; ++i)
      af[i] = *reinterpret_cast<const bf16x8*>(atile + (i * 10 + kc) * 512);
#pragma unroll
    for (int ns = 0; ns < 4; ++ns)
      bf[ns] = *reinterpret_cast<const bf16x8*>(btile + (ns * 10 + kc) * 512);
    if (z == 2) {
#pragma unroll
      for (int i = 0; i < 4; ++i)
#pragma unroll
        for (int ns = 0; ns < 4; ++ns)
          acc[i][ns] = mfma32(af[i], bf[ns], acc[i][ns]);
    } else {
#pragma unroll
      for (int i = 0; i < 4; ++i)
#pragma unroll
        for (int ns = 0; ns < 4; ++ns)
          acc[i][ns] = mfma32(bf[ns], af[i], acc[i][ns]);
    }
  }

  const float QSCALE = 0.18033688011112042f;  // 0.125 * log2(e)
  const int b = m0 >> 11;
  const int bh = b * 5 + h;
  const float* eb = edge + (size_t)((b + h) & 3) * 2048;
  const int nwb = m0 & 2047;

  if (z == 0) {
#pragma unroll
    for (int i = 0; i < 4; ++i) {
      const int n = nwb + i * 16 + m16;
      const float e = eb[n] * QSCALE;
      ushort* dst = qp + ((size_t)bh * 2048 + n) * 64 + quad * 4;
#pragma unroll
      for (int ns = 0; ns < 4; ++ns) {
        ushort4 o = { f2bf(acc[i][ns][0] * e), f2bf(acc[i][ns][1] * e),
                      f2bf(acc[i][ns][2] * e), f2bf(acc[i][ns][3] * e) };
        *reinterpret_cast<ushort4*>(dst + ns * 16) = o;
      }
    }
  } else if (z == 1) {
#pragma unroll
    for (int i = 0; i < 4; ++i) {
      const int j = nwb + i * 16 + m16;
      const float e = eb[j];
      const size_t base = (size_t)bh * 131072 +
                          (size_t)((m0 >> 4) + i & 127) * 1024;
#pragma unroll
      for (int ns = 0; ns < 4; ++ns) {
        size_t a0 = base + (ns >> 1) * 512 +
                    ((((ns * 2 + (quad >> 1)) & 3) * 16 + m16)) * 8 +
                    (quad & 1) * 4;
        ushort4 o = { f2bf(acc[i][ns][0] * e), f2bf(acc[i][ns][1] * e),
                      f2bf(acc[i][ns][2] * e), f2bf(acc[i][ns][3] * e) };
        *reinterpret_cast<ushort4*>(kS + a0) = o;
      }
    }
  } else {
    const int jb = nwb >> 6;
#pragma unroll
    for (int i = 0; i < 4; ++i) {
      const int kb = i >> 1, e4 = (i & 1) * 4;
#pragma unroll
      for (int ns = 0; ns < 4; ++ns) {
        ushort4 o = { f2bf(acc[i][ns][0]), f2bf(acc[i][ns][1]),
                      f2bf(acc[i][ns][2]), f2bf(acc[i][ns][3]) };
        size_t addr = (size_t)bh * 131072 + (size_t)ns * 32768 +
                      (size_t)jb * 1024 + kb * 512 +
                      (quad * 16 + m16) * 8 + e4;
        *reinterpret_cast<ushort4*>(vS + addr) = o;
      }
    }
  }
}

// ---------------------------------------------------------------------------
// Kernel 2: attention, r15 flash-style QBLK=128. Grid 320 flat XCD-swizzled.
// 4 waves, each owns TWO 16-q tiles (32 q rows) over all j. K/V double-
// buffered in 32KB LDS via global_load_lds; one barrier per j64-tile.
// Each uu's 8 ds_read_b128 (K 4 + V 4) feed both q-tiles -> LDS reads and
// L2 traffic halved vs r14. ~105 VGPR -> 4 waves/SIMD, no spill.
// ---------------------------------------------------------------------------
__global__ __launch_bounds__(256, 4) void attn_kernel(
    const ushort* __restrict__ qp, const ushort* __restrict__ kS,
    const ushort* __restrict__ vS, ushort* __restrict__ ao)
{
  __shared__ ushort sm[16384];   // 2 bufs x (K 8KB + V 8KB)
  const int w = blockIdx.x;
  const int s = (w & 7) * 40 + (w >> 3);
  const int bh = s >> 4, qt = s & 15;
  const int b = bh / 5, h = bh % 5;
  const int wave = threadIdx.x >> 6, lane = threadIdx.x & 63;
  const int m16 = lane & 15, quad = lane >> 4;
  const int q0 = qt * 128;

  // this wave's 2x16 q-rows
  bf16x8 qf[2][2];
#pragma unroll
  for (int qt2 = 0; qt2 < 2; ++qt2) {
    const ushort* qrow =
        qp + ((size_t)bh * 2048 + q0 + wave * 32 + qt2 * 16 + m16) * 64;
    qf[qt2][0] = *reinterpret_cast<const bf16x8*>(qrow + quad * 8);
    qf[qt2][1] = *reinterpret_cast<const bf16x8*>(qrow + 32 + quad * 8);
  }

  const ushort* kbase = kS + (size_t)bh * 131072;  // j64 tile jt at +jt*4096
  const ushort* vbase = vS + (size_t)bh * 131072;  // dt chunk at +dt*32768 + jt*1024

  f32x4 oacc[2][4];
  float rs[2] = {0.f, 0.f};
#pragma unroll
  for (int qt2 = 0; qt2 < 2; ++qt2)
#pragma unroll
    for (int dt = 0; dt < 4; ++dt) oacc[qt2][dt] = (f32x4){0.f, 0.f, 0.f, 0.f};

  // stage j64-tile jt into buffer buf: K 8KB + V 8KB
  // (wave w stages K chunk w and V chunk dt=w; 4 GLD_LDS16 per thread)
  auto stage = [&](int jt, int buf) {
    const ushort* ks = kbase + (size_t)jt * 4096 + wave * 1024 + lane * 8;
    const ushort* vs = vbase + (size_t)wave * 32768 + (size_t)jt * 1024 + lane * 8;
    ushort* dk = &sm[buf * 8192 + wave * 1024];
    ushort* dv = &sm[buf * 8192 + 4096 + wave * 1024];
#pragma unroll
    for (int is = 0; is < 2; ++is) {
      GLD_LDS16(ks + is * 512, dk + is * 512);
      GLD_LDS16(vs + is * 512, dv + is * 512);
    }
  };

  stage(0, 0);
  __syncthreads();

  int cur = 0;
  for (int jt = 0; jt < 32; ++jt) {
    if (jt < 31) stage(jt + 1, cur ^ 1);
    const ushort* kb0 = &sm[cur * 8192];
    const ushort* vb0 = &sm[cur * 8192 + 4096];
#pragma unroll
    for (int uu = 0; uu < 2; ++uu) {
      bf16x8 kf[2][2], vf[4];
#pragma unroll
      for (int ss = 0; ss < 2; ++ss)
#pragma unroll
        for (int hf = 0; hf < 2; ++hf)
          kf[ss][hf] = *reinterpret_cast<const bf16x8*>(
              kb0 + uu * 2048 + ss * 1024 + hf * 512 + lane * 8);
#pragma unroll
      for (int dt = 0; dt < 4; ++dt)
        vf[dt] = *reinterpret_cast<const bf16x8*>(
            vb0 + dt * 1024 + uu * 512 + lane * 8);

#pragma unroll
      for (int qt2 = 0; qt2 < 2; ++qt2) {
        f32x4 st0 = (f32x4){0.f, 0.f, 0.f, 0.f};
        f32x4 st1 = (f32x4){0.f, 0.f, 0.f, 0.f};
        st0 = mfma32(kf[0][0], qf[qt2][0], st0);
        st0 = mfma32(kf[0][1], qf[qt2][1], st0);
        st1 = mfma32(kf[1][0], qf[qt2][0], st1);
        st1 = mfma32(kf[1][1], qf[qt2][1], st1);
        unsigned b0 = __float_as_uint(fexp2(st0[0]));
        unsigned b1 = __float_as_uint(fexp2(st0[1]));
        unsigned b2 = __float_as_uint(fexp2(st0[2]));
        unsigned b3 = __float_as_uint(fexp2(st0[3]));
        unsigned b4 = __float_as_uint(fexp2(st1[0]));
        unsigned b5 = __float_as_uint(fexp2(st1[1]));
        unsigned b6 = __float_as_uint(fexp2(st1[2]));
        unsigned b7 = __float_as_uint(fexp2(st1[3]));
        // rowsum of TRUNCATED P (matches PV numerator quantization exactly)
        float t0 = __uint_as_float(b0 & 0xffff0000u);
        float t1 = __uint_as_float(b1 & 0xffff0000u);
        float t2 = __uint_as_float(b2 & 0xffff0000u);
        float t3 = __uint_as_float(b3 & 0xffff0000u);
        float t4 = __uint_as_float(b4 & 0xffff0000u);
        float t5 = __uint_as_float(b5 & 0xffff0000u);
        float t6 = __uint_as_float(b6 & 0xffff0000u);
        float t7 = __uint_as_float(b7 & 0xffff0000u);
        rs[qt2] += ((t0 + t1) + (t2 + t3)) + ((t4 + t5) + (t6 + t7));
        union { unsigned u[4]; bf16x8 v; } pk;
        pk.u[0] = __builtin_amdgcn_perm(b1, b0, 0x07060302u);
        pk.u[1] = __builtin_amdgcn_perm(b3, b2, 0x07060302u);
        pk.u[2] = __builtin_amdgcn_perm(b5, b4, 0x07060302u);
        pk.u[3] = __builtin_amdgcn_perm(b7, b6, 0x07060302u);
#pragma unroll
        for (int dt = 0; dt < 4; ++dt)
          oacc[qt2][dt] = mfma32(vf[dt], pk.v, oacc[qt2][dt]);
      }
    }
    __syncthreads();   // drains vmcnt (stage done) + lgkm; fences buffer swap
    cur ^= 1;
  }

#pragma unroll
  for (int qt2 = 0; qt2 < 2; ++qt2) {
    // full rowsum: reduce across the 4 quads sharing m16
    float r = rs[qt2];
    r += __shfl_xor(r, 16, 64);
    r += __shfl_xor(r, 32, 64);
    const float inv = 1.0f / r;

    const int mt2 = b * 128 + qt * 8 + wave * 2 + qt2;
#pragma unroll
    for (int dt = 0; dt < 4; ++dt) {
      f32x4 a = oacc[qt2][dt];
      unsigned r0 = f2bf(a[0] * inv), r1 = f2bf(a[1] * inv);
      unsigned r2 = f2bf(a[2] * inv), r3 = f2bf(a[3] * inv);
      uint2 ww;
      ww.x = r0 | (r1 << 16);
      ww.y = r2 | (r3 << 16);
      size_t addr = (size_t)(mt2 * 10 + h * 2 + (dt >> 1)) * 512 +
                    ((((dt & 1) * 2 + (quad >> 1)) * 16 + m16)) * 8 +
                    (quad & 1) * 4;
      *reinterpret_cast<uint2*>(ao + addr) = ww;
    }
  }
}

// ---------------------------------------------------------------------------
// Kernel 3: output projection, swapped operands; r11: 4-wave blocks with
// wave = 32m x 64n -> 1280 waves (full SIMD coverage vs 640 before).
// grid 320 flat XCD-swizzled -> (mg 0..63, ct 0..4); block covers 128m.
// ---------------------------------------------------------------------------
__global__ __launch_bounds__(256, 3) void oproj_gemm(
    const ushort* __restrict__ ao, const ushort* __restrict__ wt,
    const float* __restrict__ bo, float* __restrict__ out)
{
  const int w = blockIdx.x;
  const int s = (w & 7) * 40 + (w >> 3);
  const int mg = s / 5, ct = s % 5;
  const int wave = threadIdx.x >> 6, lane = threadIdx.x & 63;
  const int m16 = lane & 15, quad = lane >> 4;
  const int m0 = mg * 128 + wave * 32;
  const int n0 = ct * 64;
  const ushort* atile = ao + (size_t)(m0 >> 4) * 5120 + lane * 8;
  const ushort* btile = wt + (size_t)3 * 102400 + (size_t)(ct * 4) * 5120 + lane * 8;

  f32x4 acc[2][4];
#pragma unroll
  for (int i = 0; i < 2; ++i)
#pragma unroll
    for (int ns = 0; ns < 4; ++ns) acc[i][ns] = (f32x4){0.f, 0.f, 0.f, 0.f};

#pragma unroll
  for (int kc = 0; kc < 10; ++kc) {
    bf16x8 af[2], bf[4];
#pragma unroll
    for (int i = 0; i < 2; ++i)
      af[i] = *reinterpret_cast<const bf16x8*>(atile + (i * 10 + kc) * 512);
#pragma unroll
    for (int ns = 0; ns < 4; ++ns)
      bf[ns] = *reinterpret_cast<const bf16x8*>(btile + (ns * 10 + kc) * 512);
    // swapped: lane holds out-row = m16 within i-tile, 4 consecutive cols
#pragma unroll
    for (int i = 0; i < 2; ++i)
#pragma unroll
      for (int ns = 0; ns < 4; ++ns)
        acc[i][ns] = mfma32(bf[ns], af[i], acc[i][ns]);
  }

  float4 bb[4];
#pragma unroll
  for (int ns = 0; ns < 4; ++ns)
    bb[ns] = *reinterpret_cast<const float4*>(bo + n0 + ns * 16 + quad * 4);
#pragma unroll
  for (int i = 0; i < 2; ++i) {
    const int mrow = m0 + i * 16 + m16;
#pragma unroll
    for (int ns = 0; ns < 4; ++ns) {
      float4 o;
      o.x = acc[i][ns][0] + bb[ns].x;
      o.y = acc[i][ns][1] + bb[ns].y;
      o.z = acc[i][ns][2] + bb[ns].z;
      o.w = acc[i][ns][3] + bb[ns].w;
      *reinterpret_cast<float4*>(
          out + (size_t)mrow * 320 + n0 + ns * 16 + quad * 4) = o;
    }
  }
}

// ---------------------------------------------------------------------------
extern "C" void kernel_launch(void* const* d_in, const int* in_sizes, int n_in,
                              void* d_out, int out_size, void* d_ws, size_t ws_size,
                              hipStream_t stream) {
  const float* x    = (const float*)d_in[0];
  const float* edge = (const float*)d_in[1];
  const float* Wq   = (const float*)d_in[2];
  const float* Wk   = (const float*)d_in[3];
  const float* Wv   = (const float*)d_in[4];
  const float* Wo   = (const float*)d_in[5];
  const float* bo   = (const float*)d_in[6];
  float* out = (float*)d_out;

  ushort* xb = (ushort*)d_ws;                       // 8192*320
  ushort* wt = xb + (size_t)8192 * 320;             // 4*320*320
  ushort* qp = wt + (size_t)4 * 320 * 320;          // 20*2048*64
  ushort* kS = qp + (size_t)20 * 2048 * 64;
  ushort* vS = kS + (size_t)20 * 2048 * 64;
  ushort* ao = vS + (size_t)20 * 2048 * 64;

  prep_kernel<<<3360, 256, 0, stream>>>(x, Wq, Wk, Wv, Wo, xb, wt);
  qkv_gemm<<<480, 256, 0, stream>>>(xb, edge, wt, qp, kS, vS);
  attn_kernel<<<320, 256, 0, stream>>>(qp, kS, vS, ao);
  oproj_gemm<<<320, 256, 0, stream>>>(ao, wt, bo, out);
}

// Round 6
// 131.603 us; speedup vs baseline: 1.1296x; 1.1296x over previous
//
#include <hip/hip_runtime.h>
#include <hip/hip_bf16.h>
#include <math.h>

// B=4, N=2048, C=320, H=5, D=64, INNER=320, BH=20
// logit = (q*0.125*log2e*e_i) . (k*e_j); softmax via exp2 (bounded, no max).
// e_bh = edge[(b+h)%4]  (batch-minor edge tiling vs batch-major heads)
//
// Fragment-major layouts (every main-loop load = lane-contiguous b128):
//  xb  tiles (mt2=m/16, kc=k/32): elem (qq*16+mm)*8+e  = x[m][k], qq=(k%32)>>3
//  wt  tiles (z, nt2=n/16, kc):   elem (qq*16+nn)*8+e  = W[k][n]
//  kS  [bh][j/16][d/32][slot]:    slot ((d>>3)&3)*16+(j&15), e=d&7
//  vS  [bh][d/16][j/64][kb][slot]: PV mfma32 A-frag order (see r3 notes)
//  ao  tiles like xb (A-operand of oproj)
//  qp  row-major [bh][n][64]
//
// r17: (qw,jw) wave roles. r15/r16 post-mortem: QBLK=128 @ 320 blocks had
// occupancy 10% (1.25 waves/SIMD) -> latency-exposed (MfmaUtil 13.5%),
// 58.5us despite halved LDS traffic; r14 (640 blk, 2.5 waves/SIMD) was
// 36us with 2x traffic. Fix keeps BOTH: 640 blocks x 4 waves, wave =
// (qw = wave>>1 owns 32 q rows, jw = wave&1 takes uu==jw in each staged
// j64 tile). Per-wave LDS reads halve (8 b128/jt feed 2 q-tiles); all
// waves active at every barrier; tiny 2-barrier LDS combine (jw pair)
// at the end. Per-CU budget: LDS pipe ~19us, MFMA 10.4, exp ~4 -> ~22-27us.
// Ledger: 2 poison fills ~83us + prep/qkv/oproj ~9us fixed; attn is the
// only lever; must beat 36us (r9-equivalent) to beat the 124us baseline.

typedef short bf16x8 __attribute__((ext_vector_type(8)));
typedef float f32x4 __attribute__((ext_vector_type(4)));

static __device__ __forceinline__ ushort f2bf(float f) {
  union { float f; unsigned u; } v; v.f = f;
  unsigned r = (v.u + 0x7fffu + ((v.u >> 16) & 1u)) >> 16;
  return (ushort)r;
}
static __device__ __forceinline__ float fexp2(float x) {
#if __has_builtin(__builtin_amdgcn_exp2f)
  return __builtin_amdgcn_exp2f(x);
#else
  return exp2f(x);
#endif
}
static __device__ __forceinline__ f32x4 mfma32(bf16x8 a, bf16x8 b, f32x4 c) {
  return __builtin_amdgcn_mfma_f32_16x16x32_bf16(a, b, c, 0, 0, 0);
}

#define GLD_LDS16(gsrc, ldst)                                                  \
  __builtin_amdgcn_global_load_lds(                                            \
      (const __attribute__((address_space(1))) unsigned int*)(gsrc),           \
      (__attribute__((address_space(3))) unsigned int*)(ldst), 16, 0, 0)

// ---------------------------------------------------------------------------
// Prep (fused): flat grid 3360. (verbatim r9)
// ---------------------------------------------------------------------------
__global__ __launch_bounds__(256) void prep_kernel(
    const float* __restrict__ x,
    const float* __restrict__ Wq, const float* __restrict__ Wk,
    const float* __restrict__ Wv, const float* __restrict__ Wo,
    ushort* __restrict__ xb, ushort* __restrict__ wt)
{
  const int w = blockIdx.x;
  if (w < 2560) {
    const int t = threadIdx.x;
    const int mt2 = w / 5;
    const int kc = (w % 5) * 2 + (t >> 7);
    const int f = (t & 127) * 4;
    const int qq = f >> 7, mm = (f >> 3) & 15, e0 = f & 7;
    float4 v = *reinterpret_cast<const float4*>(
        x + (size_t)(mt2 * 16 + mm) * 320 + kc * 32 + qq * 8 + e0);
    ushort4 o = { f2bf(v.x), f2bf(v.y), f2bf(v.z), f2bf(v.w) };
    *reinterpret_cast<ushort4*>(xb + (size_t)(mt2 * 10 + kc) * 512 + f) = o;
  } else {
    const int w2 = w - 2560;
    const int nt2 = w2 % 20, kc = (w2 / 20) % 10, z = w2 / 200;
    const float* W = z == 0 ? Wq : z == 1 ? Wk : z == 2 ? Wv : Wo;
    const int f = threadIdx.x * 2;
    const int qq = f >> 7, nn = (f >> 3) & 15, e0 = f & 7;
    const int k = kc * 32 + qq * 8 + e0, n = nt2 * 16 + nn;
    float v0 = W[(size_t)k * 320 + n];
    float v1 = W[(size_t)(k + 1) * 320 + n];
    ushort2 o = { f2bf(v0), f2bf(v1) };
    *reinterpret_cast<ushort2*>(
        wt + (size_t)z * 102400 + (size_t)(nt2 * 10 + kc) * 512 + f) = o;
  }
}

// ---------------------------------------------------------------------------
// Kernel 1: QKV projection big-tile (verbatim r9).
// ---------------------------------------------------------------------------
__global__ __launch_bounds__(256, 3) void qkv_gemm(
    const ushort* __restrict__ xb, const float* __restrict__ edge,
    const ushort* __restrict__ wt,
    ushort* __restrict__ qp, ushort* __restrict__ kS, ushort* __restrict__ vS)
{
  const int w = blockIdx.x;
  const int s = (w & 7) * 60 + (w >> 3);
  const int mg = s / 15, zh = s % 15;
  const int z = zh / 5, h = zh % 5;
  const int wave = threadIdx.x >> 6, lane = threadIdx.x & 63;
  const int m16 = lane & 15, quad = lane >> 4;
  const int m0 = mg * 256 + wave * 64;
  const ushort* atile = xb + (size_t)(m0 >> 4) * 5120 + lane * 8;
  const ushort* btile = wt + (size_t)z * 102400 + (size_t)(h * 4) * 5120 + lane * 8;

  f32x4 acc[4][4];
#pragma unroll
  for (int i = 0; i < 4; ++i)
#pragma unroll
    for (int ns = 0; ns < 4; ++ns) acc[i][ns] = (f32x4){0.f, 0.f, 0.f, 0.f};

#pragma unroll
  for (int kc = 0; kc < 10; ++kc) {
    bf16x8 af[4], bf[4];
#pragma unroll
    for (int i = 0; i < 4; ++i)
      af[i] = *reinterpret_cast<const bf16x8*>(atile + (i * 10 + kc) * 512);
#pragma unroll
    for (int ns = 0; ns < 4; ++ns)
      bf[ns] = *reinterpret_cast<const bf16x8*>(btile + (ns * 10 + kc) * 512);
    if (z == 2) {
#pragma unroll
      for (int i = 0; i < 4; ++i)
#pragma unroll
        for (int ns = 0; ns < 4; ++ns)
          acc[i][ns] = mfma32(af[i], bf[ns], acc[i][ns]);
    } else {
#pragma unroll
      for (int i = 0; i < 4; ++i)
#pragma unroll
        for (int ns = 0; ns < 4; ++ns)
          acc[i][ns] = mfma32(bf[ns], af[i], acc[i][ns]);
    }
  }

  const float QSCALE = 0.18033688011112042f;  // 0.125 * log2(e)
  const int b = m0 >> 11;
  const int bh = b * 5 + h;
  const float* eb = edge + (size_t)((b + h) & 3) * 2048;
  const int nwb = m0 & 2047;

  if (z == 0) {
#pragma unroll
    for (int i = 0; i < 4; ++i) {
      const int n = nwb + i * 16 + m16;
      const float e = eb[n] * QSCALE;
      ushort* dst = qp + ((size_t)bh * 2048 + n) * 64 + quad * 4;
#pragma unroll
      for (int ns = 0; ns < 4; ++ns) {
        ushort4 o = { f2bf(acc[i][ns][0] * e), f2bf(acc[i][ns][1] * e),
                      f2bf(acc[i][ns][2] * e), f2bf(acc[i][ns][3] * e) };
        *reinterpret_cast<ushort4*>(dst + ns * 16) = o;
      }
    }
  } else if (z == 1) {
#pragma unroll
    for (int i = 0; i < 4; ++i) {
      const int j = nwb + i * 16 + m16;
      const float e = eb[j];
      const size_t base = (size_t)bh * 131072 +
                          (size_t)((m0 >> 4) + i & 127) * 1024;
#pragma unroll
      for (int ns = 0; ns < 4; ++ns) {
        size_t a0 = base + (ns >> 1) * 512 +
                    ((((ns * 2 + (quad >> 1)) & 3) * 16 + m16)) * 8 +
                    (quad & 1) * 4;
        ushort4 o = { f2bf(acc[i][ns][0] * e), f2bf(acc[i][ns][1] * e),
                      f2bf(acc[i][ns][2] * e), f2bf(acc[i][ns][3] * e) };
        *reinterpret_cast<ushort4*>(kS + a0) = o;
      }
    }
  } else {
    const int jb = nwb >> 6;
#pragma unroll
    for (int i = 0; i < 4; ++i) {
      const int kb = i >> 1, e4 = (i & 1) * 4;
#pragma unroll
      for (int ns = 0; ns < 4; ++ns) {
        ushort4 o = { f2bf(acc[i][ns][0]), f2bf(acc[i][ns][1]),
                      f2bf(acc[i][ns][2]), f2bf(acc[i][ns][3]) };
        size_t addr = (size_t)bh * 131072 + (size_t)ns * 32768 +
                      (size_t)jb * 1024 + kb * 512 +
                      (quad * 16 + m16) * 8 + e4;
        *reinterpret_cast<ushort4*>(vS + addr) = o;
      }
    }
  }
}

// ---------------------------------------------------------------------------
// Kernel 2: attention, r17. Grid 640 flat XCD-swizzled, 64 q per block.
// Wave roles: qw = wave>>1 owns q rows [q0+qw*32, +32) (2 16-q tiles);
// jw = wave&1 computes only uu==jw of each staged j64 tile. K/V double-
// buffered in LDS via global_load_lds (verbatim r14 staging); one barrier
// per jt. Epilogue: jw=1 dumps partial oacc/rs to LDS (sm reused, 17KB),
// jw=0 combines and writes ao. ~105 VGPR -> (256,4), 2560 waves.
// ---------------------------------------------------------------------------
__global__ __launch_bounds__(256, 4) void attn_kernel(
    const ushort* __restrict__ qp, const ushort* __restrict__ kS,
    const ushort* __restrict__ vS, ushort* __restrict__ ao)
{
  __shared__ ushort sm[16384];   // 2 bufs x (K 8KB + V 8KB) = 32KB
  const int w = blockIdx.x;
  const int s = (w & 7) * 80 + (w >> 3);
  const int bh = s >> 5, qt = s & 31;
  const int b = bh / 5, h = bh % 5;
  const int wave = threadIdx.x >> 6, lane = threadIdx.x & 63;
  const int m16 = lane & 15, quad = lane >> 4;
  const int qw = wave >> 1, jw = wave & 1;
  const int q0 = qt * 64;

  // this wave's 2x16 q-rows (qw selects the 32-row half of the block)
  bf16x8 qf[2][2];
#pragma unroll
  for (int qt2 = 0; qt2 < 2; ++qt2) {
    const ushort* qrow =
        qp + ((size_t)bh * 2048 + q0 + qw * 32 + qt2 * 16 + m16) * 64;
    qf[qt2][0] = *reinterpret_cast<const bf16x8*>(qrow + quad * 8);
    qf[qt2][1] = *reinterpret_cast<const bf16x8*>(qrow + 32 + quad * 8);
  }

  const ushort* kbase = kS + (size_t)bh * 131072;  // j64 tile jt at +jt*4096
  const ushort* vbase = vS + (size_t)bh * 131072;  // dt chunk at +dt*32768 + jt*1024

  f32x4 oacc[2][4];
  float rs[2] = {0.f, 0.f};
#pragma unroll
  for (int qt2 = 0; qt2 < 2; ++qt2)
#pragma unroll
    for (int dt = 0; dt < 4; ++dt) oacc[qt2][dt] = (f32x4){0.f, 0.f, 0.f, 0.f};

  // stage j64-tile jt into buffer buf: K 8KB + V 8KB
  // (wave stages K j16-subtile=wave and V dt-chunk=wave; 4 GLD_LDS16/thread)
  auto stage = [&](int jt, int buf) {
    const ushort* ks = kbase + (size_t)jt * 4096 + wave * 1024 + lane * 8;
    const ushort* vs = vbase + (size_t)wave * 32768 + (size_t)jt * 1024 + lane * 8;
    ushort* dk = &sm[buf * 8192 + wave * 1024];
    ushort* dv = &sm[buf * 8192 + 4096 + wave * 1024];
#pragma unroll
    for (int is = 0; is < 2; ++is) {
      GLD_LDS16(ks + is * 512, dk + is * 512);
      GLD_LDS16(vs + is * 512, dv + is * 512);
    }
  };

  stage(0, 0);
  __syncthreads();

  int cur = 0;
  for (int jt = 0; jt < 32; ++jt) {
    if (jt < 31) stage(jt + 1, cur ^ 1);
    const ushort* kb0 = &sm[cur * 8192];
    const ushort* vb0 = &sm[cur * 8192 + 4096];
    // this wave's uu is fixed: uu == jw (partner wave takes the other half)
    bf16x8 kf[2][2], vf[4];
#pragma unroll
    for (int ss = 0; ss < 2; ++ss)
#pragma unroll
      for (int hf = 0; hf < 2; ++hf)
        kf[ss][hf] = *reinterpret_cast<const bf16x8*>(
            kb0 + jw * 2048 + ss * 1024 + hf * 512 + lane * 8);
#pragma unroll
    for (int dt = 0; dt < 4; ++dt)
      vf[dt] = *reinterpret_cast<const bf16x8*>(
          vb0 + dt * 1024 + jw * 512 + lane * 8);

#pragma unroll
    for (int qt2 = 0; qt2 < 2; ++qt2) {
      f32x4 st0 = (f32x4){0.f, 0.f, 0.f, 0.f};
      f32x4 st1 = (f32x4){0.f, 0.f, 0.f, 0.f};
      st0 = mfma32(kf[0][0], qf[qt2][0], st0);
      st0 = mfma32(kf[0][1], qf[qt2][1], st0);
      st1 = mfma32(kf[1][0], qf[qt2][0], st1);
      st1 = mfma32(kf[1][1], qf[qt2][1], st1);
      unsigned b0 = __float_as_uint(fexp2(st0[0]));
      unsigned b1 = __float_as_uint(fexp2(st0[1]));
      unsigned b2 = __float_as_uint(fexp2(st0[2]));
      unsigned b3 = __float_as_uint(fexp2(st0[3]));
      unsigned b4 = __float_as_uint(fexp2(st1[0]));
      unsigned b5 = __float_as_uint(fexp2(st1[1]));
      unsigned b6 = __float_as_uint(fexp2(st1[2]));
      unsigned b7 = __float_as_uint(fexp2(st1[3]));
      // rowsum of TRUNCATED P (matches PV numerator quantization exactly)
      float t0 = __uint_as_float(b0 & 0xffff0000u);
      float t1 = __uint_as_float(b1 & 0xffff0000u);
      float t2 = __uint_as_float(b2 & 0xffff0000u);
      float t3 = __uint_as_float(b3 & 0xffff0000u);
      float t4 = __uint_as_float(b4 & 0xffff0000u);
      float t5 = __uint_as_float(b5 & 0xffff0000u);
      float t6 = __uint_as_float(b6 & 0xffff0000u);
      float t7 = __uint_as_float(b7 & 0xffff0000u);
      rs[qt2] += ((t0 + t1) + (t2 + t3)) + ((t4 + t5) + (t6 + t7));
      union { unsigned u[4]; bf16x8 v; } pk;
      pk.u[0] = __builtin_amdgcn_perm(b1, b0, 0x07060302u);
      pk.u[1] = __builtin_amdgcn_perm(b3, b2, 0x07060302u);
      pk.u[2] = __builtin_amdgcn_perm(b5, b4, 0x07060302u);
      pk.u[3] = __builtin_amdgcn_perm(b7, b6, 0x07060302u);
#pragma unroll
      for (int dt = 0; dt < 4; ++dt)
        oacc[qt2][dt] = mfma32(vf[dt], pk.v, oacc[qt2][dt]);
    }
    __syncthreads();   // drains vmcnt (stage done) + lgkm; fences buffer swap
    cur ^= 1;
  }

  // combine jw pair via LDS (sm reused: 16KB f32x4 partials + 1KB rs)
  f32x4* lov = reinterpret_cast<f32x4*>(sm);
  float* lrsf = reinterpret_cast<float*>(sm + 8192);   // byte offset 16KB
  if (jw) {
#pragma unroll
    for (int qt2 = 0; qt2 < 2; ++qt2) {
#pragma unroll
      for (int dt = 0; dt < 4; ++dt)
        lov[(qw * 8 + qt2 * 4 + dt) * 64 + lane] = oacc[qt2][dt];
      lrsf[(qw * 2 + qt2) * 64 + lane] = rs[qt2];
    }
  }
  __syncthreads();
  if (!jw) {
#pragma unroll
    for (int qt2 = 0; qt2 < 2; ++qt2) {
      float r = rs[qt2] + lrsf[(qw * 2 + qt2) * 64 + lane];
      r += __shfl_xor(r, 16, 64);
      r += __shfl_xor(r, 32, 64);
      const float inv = 1.0f / r;

      const int mt2 = b * 128 + qt * 4 + qw * 2 + qt2;
#pragma unroll
      for (int dt = 0; dt < 4; ++dt) {
        f32x4 a = oacc[qt2][dt];
        a += lov[(qw * 8 + qt2 * 4 + dt) * 64 + lane];
        unsigned r0 = f2bf(a[0] * inv), r1 = f2bf(a[1] * inv);
        unsigned r2 = f2bf(a[2] * inv), r3 = f2bf(a[3] * inv);
        uint2 ww;
        ww.x = r0 | (r1 << 16);
        ww.y = r2 | (r3 << 16);
        size_t addr = (size_t)(mt2 * 10 + h * 2 + (dt >> 1)) * 512 +
                      ((((dt & 1) * 2 + (quad >> 1)) * 16 + m16)) * 8 +
                      (quad & 1) * 4;
        *reinterpret_cast<uint2*>(ao + addr) = ww;
      }
    }
  }
}

// ---------------------------------------------------------------------------
// Kernel 3: output projection, swapped operands; r11: 4-wave blocks with
// wave = 32m x 64n -> 1280 waves (full SIMD coverage vs 640 before).
// grid 320 flat XCD-swizzled -> (mg 0..63, ct 0..4); block covers 128m.
// ---------------------------------------------------------------------------
__global__ __launch_bounds__(256, 3) void oproj_gemm(
    const ushort* __restrict__ ao, const ushort* __restrict__ wt,
    const float* __restrict__ bo, float* __restrict__ out)
{
  const int w = blockIdx.x;
  const int s = (w & 7) * 40 + (w >> 3);
  const int mg = s / 5, ct = s % 5;
  const int wave = threadIdx.x >> 6, lane = threadIdx.x & 63;
  const int m16 = lane & 15, quad = lane >> 4;
  const int m0 = mg * 128 + wave * 32;
  const int n0 = ct * 64;
  const ushort* atile = ao + (size_t)(m0 >> 4) * 5120 + lane * 8;
  const ushort* btile = wt + (size_t)3 * 102400 + (size_t)(ct * 4) * 5120 + lane * 8;

  f32x4 acc[2][4];
#pragma unroll
  for (int i = 0; i < 2; ++i)
#pragma unroll
    for (int ns = 0; ns < 4; ++ns) acc[i][ns] = (f32x4){0.f, 0.f, 0.f, 0.f};

#pragma unroll
  for (int kc = 0; kc < 10; ++kc) {
    bf16x8 af[2], bf[4];
#pragma unroll
    for (int i = 0; i < 2; ++i)
      af[i] = *reinterpret_cast<const bf16x8*>(atile + (i * 10 + kc) * 512);
#pragma unroll
    for (int ns = 0; ns < 4; ++ns)
      bf[ns] = *reinterpret_cast<const bf16x8*>(btile + (ns * 10 + kc) * 512);
    // swapped: lane holds out-row = m16 within i-tile, 4 consecutive cols
#pragma unroll
    for (int i = 0; i < 2; ++i)
#pragma unroll
      for (int ns = 0; ns < 4; ++ns)
        acc[i][ns] = mfma32(bf[ns], af[i], acc[i][ns]);
  }

  float4 bb[4];
#pragma unroll
  for (int ns = 0; ns < 4; ++ns)
    bb[ns] = *reinterpret_cast<const float4*>(bo + n0 + ns * 16 + quad * 4);
#pragma unroll
  for (int i = 0; i < 2; ++i) {
    const int mrow = m0 + i * 16 + m16;
#pragma unroll
    for (int ns = 0; ns < 4; ++ns) {
      float4 o;
      o.x = acc[i][ns][0] + bb[ns].x;
      o.y = acc[i][ns][1] + bb[ns].y;
      o.z = acc[i][ns][2] + bb[ns].z;
      o.w = acc[i][ns][3] + bb[ns].w;
      *reinterpret_cast<float4*>(
          out + (size_t)mrow * 320 + n0 + ns * 16 + quad * 4) = o;
    }
  }
}

// ---------------------------------------------------------------------------
extern "C" void kernel_launch(void* const* d_in, const int* in_sizes, int n_in,
                              void* d_out, int out_size, void* d_ws, size_t ws_size,
                              hipStream_t stream) {
  const float* x    = (const float*)d_in[0];
  const float* edge = (const float*)d_in[1];
  const float* Wq   = (const float*)d_in[2];
  const float* Wk   = (const float*)d_in[3];
  const float* Wv   = (const float*)d_in[4];
  const float* Wo   = (const float*)d_in[5];
  const float* bo   = (const float*)d_in[6];
  float* out = (float*)d_out;

  ushort* xb = (ushort*)d_ws;                       // 8192*320
  ushort* wt = xb + (size_t)8192 * 320;             // 4*320*320
  ushort* qp = wt + (size_t)4 * 320 * 320;          // 20*2048*64
  ushort* kS = qp + (size_t)20 * 2048 * 64;
  ushort* vS = kS + (size_t)20 * 2048 * 64;
  ushort* ao = vS + (size_t)20 * 2048 * 64;

  prep_kernel<<<3360, 256, 0, stream>>>(x, Wq, Wk, Wv, Wo, xb, wt);
  qkv_gemm<<<480, 256, 0, stream>>>(xb, edge, wt, qp, kS, vS);
  attn_kernel<<<640, 256, 0, stream>>>(qp, kS, vS, ao);
  oproj_gemm<<<320, 256, 0, stream>>>(ao, wt, bo, out);
}

// Round 7
// 131.047 us; speedup vs baseline: 1.1344x; 1.0042x over previous
//
#include <hip/hip_runtime.h>
#include <hip/hip_bf16.h>
#include <math.h>

// B=4, N=2048, C=320, H=5, D=64, INNER=320, BH=20
// logit = (q*0.125*log2e*e_i) . (k*e_j); softmax via exp2 (bounded, no max).
// e_bh = edge[(b+h)%4]  (batch-minor edge tiling vs batch-major heads)
//
// Fragment-major layouts (every main-loop load = lane-contiguous b128):
//  xb  tiles (mt2=m/16, kc=k/32): elem (qq*16+mm)*8+e  = x[m][k], qq=(k%32)>>3
//  wt  tiles (z, nt2=n/16, kc):   elem (qq*16+nn)*8+e  = W[k][n]
//  kS  [bh][j/16][d/32][slot]:    slot ((d>>3)&3)*16+(j&15), e=d&7
//  vS  [bh][d/16][j/64][kb][slot]: PV mfma32 A-frag order (see r3 notes)
//  ao  tiles like xb (A-operand of oproj)
//  qp  row-major [bh][n][64]
//
// r18: counted-vmcnt pipeline (T4). r17 post-mortem: three structures
// (r9 reg j-split, r14 flash, r17 flash+jw) all land ~36us while every
// throughput budget (MFMA 10.3, LDS 13-19, VALU 6, L2 10us) is far lower
// and halving ds_read moved nothing -> binder is the per-jt __syncthreads
// which lowers to s_waitcnt vmcnt(0) (drains the JUST-ISSUED stage loads,
// ~500-700cy stall x 32 jt). Fix: 3 LDS bufs (48KB), raw s_barrier +
// inline s_waitcnt vmcnt(4) (stage(jt+1)'s 4 loads stay in flight across
// the barrier; only stage(jt)'s oldest 4 are waited). sched_barrier(0)
// pins + laundered LDS base (asm "+v") keep compiler from hoisting
// ds_reads above the barrier (rule #18/#21). Hazard audit: stage(jt+2)
// writes the buffer read at jt-1, fenced by the jt barrier; tail peeled
// with vmcnt(0); __syncthreads before epilogue LDS reuse.
// Ledger: 2 poison fills ~86us + prep/qkv/oproj ~9us fixed; attn is the
// only lever; must beat ~36us to beat the 124us session baseline.

typedef short bf16x8 __attribute__((ext_vector_type(8)));
typedef float f32x4 __attribute__((ext_vector_type(4)));

static __device__ __forceinline__ ushort f2bf(float f) {
  union { float f; unsigned u; } v; v.f = f;
  unsigned r = (v.u + 0x7fffu + ((v.u >> 16) & 1u)) >> 16;
  return (ushort)r;
}
static __device__ __forceinline__ float fexp2(float x) {
#if __has_builtin(__builtin_amdgcn_exp2f)
  return __builtin_amdgcn_exp2f(x);
#else
  return exp2f(x);
#endif
}
static __device__ __forceinline__ f32x4 mfma32(bf16x8 a, bf16x8 b, f32x4 c) {
  return __builtin_amdgcn_mfma_f32_16x16x32_bf16(a, b, c, 0, 0, 0);
}

#define GLD_LDS16(gsrc, ldst)                                                  \
  __builtin_amdgcn_global_load_lds(                                            \
      (const __attribute__((address_space(1))) unsigned int*)(gsrc),           \
      (__attribute__((address_space(3))) unsigned int*)(ldst), 16, 0, 0)

// ---------------------------------------------------------------------------
// Prep (fused): flat grid 3360. (verbatim r9)
// ---------------------------------------------------------------------------
__global__ __launch_bounds__(256) void prep_kernel(
    const float* __restrict__ x,
    const float* __restrict__ Wq, const float* __restrict__ Wk,
    const float* __restrict__ Wv, const float* __restrict__ Wo,
    ushort* __restrict__ xb, ushort* __restrict__ wt)
{
  const int w = blockIdx.x;
  if (w < 2560) {
    const int t = threadIdx.x;
    const int mt2 = w / 5;
    const int kc = (w % 5) * 2 + (t >> 7);
    const int f = (t & 127) * 4;
    const int qq = f >> 7, mm = (f >> 3) & 15, e0 = f & 7;
    float4 v = *reinterpret_cast<const float4*>(
        x + (size_t)(mt2 * 16 + mm) * 320 + kc * 32 + qq * 8 + e0);
    ushort4 o = { f2bf(v.x), f2bf(v.y), f2bf(v.z), f2bf(v.w) };
    *reinterpret_cast<ushort4*>(xb + (size_t)(mt2 * 10 + kc) * 512 + f) = o;
  } else {
    const int w2 = w - 2560;
    const int nt2 = w2 % 20, kc = (w2 / 20) % 10, z = w2 / 200;
    const float* W = z == 0 ? Wq : z == 1 ? Wk : z == 2 ? Wv : Wo;
    const int f = threadIdx.x * 2;
    const int qq = f >> 7, nn = (f >> 3) & 15, e0 = f & 7;
    const int k = kc * 32 + qq * 8 + e0, n = nt2 * 16 + nn;
    float v0 = W[(size_t)k * 320 + n];
    float v1 = W[(size_t)(k + 1) * 320 + n];
    ushort2 o = { f2bf(v0), f2bf(v1) };
    *reinterpret_cast<ushort2*>(
        wt + (size_t)z * 102400 + (size_t)(nt2 * 10 + kc) * 512 + f) = o;
  }
}

// ---------------------------------------------------------------------------
// Kernel 1: QKV projection big-tile (verbatim r9).
// ---------------------------------------------------------------------------
__global__ __launch_bounds__(256, 3) void qkv_gemm(
    const ushort* __restrict__ xb, const float* __restrict__ edge,
    const ushort* __restrict__ wt,
    ushort* __restrict__ qp, ushort* __restrict__ kS, ushort* __restrict__ vS)
{
  const int w = blockIdx.x;
  const int s = (w & 7) * 60 + (w >> 3);
  const int mg = s / 15, zh = s % 15;
  const int z = zh / 5, h = zh % 5;
  const int wave = threadIdx.x >> 6, lane = threadIdx.x & 63;
  const int m16 = lane & 15, quad = lane >> 4;
  const int m0 = mg * 256 + wave * 64;
  const ushort* atile = xb + (size_t)(m0 >> 4) * 5120 + lane * 8;
  const ushort* btile = wt + (size_t)z * 102400 + (size_t)(h * 4) * 5120 + lane * 8;

  f32x4 acc[4][4];
#pragma unroll
  for (int i = 0; i < 4; ++i)
#pragma unroll
    for (int ns = 0; ns < 4; ++ns) acc[i][ns] = (f32x4){0.f, 0.f, 0.f, 0.f};

#pragma unroll
  for (int kc = 0; kc < 10; ++kc) {
    bf16x8 af[4], bf[4];
#pragma unroll
    for (int i = 0; i < 4; ++i)
      af[i] = *reinterpret_cast<const bf16x8*>(atile + (i * 10 + kc) * 512);
#pragma unroll
    for (int ns = 0; ns < 4; ++ns)
      bf[ns] = *reinterpret_cast<const bf16x8*>(btile + (ns * 10 + kc) * 512);
    if (z == 2) {
#pragma unroll
      for (int i = 0; i < 4; ++i)
#pragma unroll
        for (int ns = 0; ns < 4; ++ns)
          acc[i][ns] = mfma32(af[i], bf[ns], acc[i][ns]);
    } else {
#pragma unroll
      for (int i = 0; i < 4; ++i)
#pragma unroll
        for (int ns = 0; ns < 4; ++ns)
          acc[i][ns] = mfma32(bf[ns], af[i], acc[i][ns]);
    }
  }

  const float QSCALE = 0.18033688011112042f;  // 0.125 * log2(e)
  const int b = m0 >> 11;
  const int bh = b * 5 + h;
  const float* eb = edge + (size_t)((b + h) & 3) * 2048;
  const int nwb = m0 & 2047;

  if (z == 0) {
#pragma unroll
    for (int i = 0; i < 4; ++i) {
      const int n = nwb + i * 16 + m16;
      const float e = eb[n] * QSCALE;
      ushort* dst = qp + ((size_t)bh * 2048 + n) * 64 + quad * 4;
#pragma unroll
      for (int ns = 0; ns < 4; ++ns) {
        ushort4 o = { f2bf(acc[i][ns][0] * e), f2bf(acc[i][ns][1] * e),
                      f2bf(acc[i][ns][2] * e), f2bf(acc[i][ns][3] * e) };
        *reinterpret_cast<ushort4*>(dst + ns * 16) = o;
      }
    }
  } else if (z == 1) {
#pragma unroll
    for (int i = 0; i < 4; ++i) {
      const int j = nwb + i * 16 + m16;
      const float e = eb[j];
      const size_t base = (size_t)bh * 131072 +
                          (size_t)((m0 >> 4) + i & 127) * 1024;
#pragma unroll
      for (int ns = 0; ns < 4; ++ns) {
        size_t a0 = base + (ns >> 1) * 512 +
                    ((((ns * 2 + (quad >> 1)) & 3) * 16 + m16)) * 8 +
                    (quad & 1) * 4;
        ushort4 o = { f2bf(acc[i][ns][0] * e), f2bf(acc[i][ns][1] * e),
                      f2bf(acc[i][ns][2] * e), f2bf(acc[i][ns][3] * e) };
        *reinterpret_cast<ushort4*>(kS + a0) = o;
      }
    }
  } else {
    const int jb = nwb >> 6;
#pragma unroll
    for (int i = 0; i < 4; ++i) {
      const int kb = i >> 1, e4 = (i & 1) * 4;
#pragma unroll
      for (int ns = 0; ns < 4; ++ns) {
        ushort4 o = { f2bf(acc[i][ns][0]), f2bf(acc[i][ns][1]),
                      f2bf(acc[i][ns][2]), f2bf(acc[i][ns][3]) };
        size_t addr = (size_t)bh * 131072 + (size_t)ns * 32768 +
                      (size_t)jb * 1024 + kb * 512 +
                      (quad * 16 + m16) * 8 + e4;
        *reinterpret_cast<ushort4*>(vS + addr) = o;
      }
    }
  }
}

// ---------------------------------------------------------------------------
// Kernel 2: attention, r18. Grid 640 flat XCD-swizzled, 64 q per block.
// Wave roles: qw = wave>>1 owns 32 q rows (2 16-q tiles); jw = wave&1 takes
// uu==jw of each staged j64 tile. K/V in 3 LDS buffers (48KB) staged via
// global_load_lds with COUNTED vmcnt: per jt  [vmcnt(4); s_barrier;
// stage(jt+2); compute(jt%3)]  -- stage(jt+1)'s loads stay in flight
// across the barrier (never vmcnt(0) in the loop; T4). Epilogue combine
// of the jw pair via LDS after a full __syncthreads.
// ---------------------------------------------------------------------------
__global__ __launch_bounds__(256, 4) void attn_kernel(
    const ushort* __restrict__ qp, const ushort* __restrict__ kS,
    const ushort* __restrict__ vS, ushort* __restrict__ ao)
{
  __shared__ ushort sm[24576];   // 3 bufs x (K 8KB + V 8KB) = 48KB
  const int w = blockIdx.x;
  const int s = (w & 7) * 80 + (w >> 3);
  const int bh = s >> 5, qt = s & 31;
  const int b = bh / 5, h = bh % 5;
  const int wave = threadIdx.x >> 6, lane = threadIdx.x & 63;
  const int m16 = lane & 15, quad = lane >> 4;
  const int qw = wave >> 1, jw = wave & 1;
  const int q0 = qt * 64;

  // this wave's 2x16 q-rows (qw selects the 32-row half of the block)
  bf16x8 qf[2][2];
#pragma unroll
  for (int qt2 = 0; qt2 < 2; ++qt2) {
    const ushort* qrow =
        qp + ((size_t)bh * 2048 + q0 + qw * 32 + qt2 * 16 + m16) * 64;
    qf[qt2][0] = *reinterpret_cast<const bf16x8*>(qrow + quad * 8);
    qf[qt2][1] = *reinterpret_cast<const bf16x8*>(qrow + 32 + quad * 8);
  }

  const ushort* kbase = kS + (size_t)bh * 131072;  // j64 tile jt at +jt*4096
  const ushort* vbase = vS + (size_t)bh * 131072;  // dt chunk at +dt*32768 + jt*1024

  f32x4 oacc[2][4];
  float rs[2] = {0.f, 0.f};
#pragma unroll
  for (int qt2 = 0; qt2 < 2; ++qt2)
#pragma unroll
    for (int dt = 0; dt < 4; ++dt) oacc[qt2][dt] = (f32x4){0.f, 0.f, 0.f, 0.f};

  // stage j64-tile jt into buffer buf: K 8KB + V 8KB
  // (wave stages K j16-subtile=wave and V dt-chunk=wave; 4 GLD_LDS16/thread)
  auto stage = [&](int jt, int buf) {
    const ushort* ks = kbase + (size_t)jt * 4096 + wave * 1024 + lane * 8;
    const ushort* vs = vbase + (size_t)wave * 32768 + (size_t)jt * 1024 + lane * 8;
    ushort* dk = &sm[buf * 8192 + wave * 1024];
    ushort* dv = &sm[buf * 8192 + 4096 + wave * 1024];
#pragma unroll
    for (int is = 0; is < 2; ++is) {
      GLD_LDS16(ks + is * 512, dk + is * 512);
      GLD_LDS16(vs + is * 512, dv + is * 512);
    }
  };

  stage(0, 0);   // 4 outstanding
  stage(1, 1);   // 8 outstanding

  int cur = 0;    // buffer holding tile jt
  int nxt2 = 2;   // buffer for tile jt+2
#pragma unroll 1
  for (int jt = 0; jt < 32; ++jt) {
    // wait for the OLDEST stage (tile jt) only; tile jt+1's 4 loads stay
    // in flight across the barrier. Tail (jt=31): full drain.
    if (jt < 31) {
      asm volatile("s_waitcnt vmcnt(4)" ::: "memory");
    } else {
      asm volatile("s_waitcnt vmcnt(0)" ::: "memory");
    }
    __builtin_amdgcn_sched_barrier(0);
    __builtin_amdgcn_s_barrier();   // all waves: stage(jt) landed, compute(jt-1) done
    __builtin_amdgcn_sched_barrier(0);
    // launder the read base so ds_reads are data-dependent on a value
    // defined after the barrier (no IR-level hoist above it)
    int curoff = cur * 8192;
    asm volatile("" : "+v"(curoff));
    // stage(jt+2) overwrites the buffer read at jt-1 (all waves past the
    // barrier => done with it). Never issued before the barrier.
    if (jt + 2 < 32) stage(jt + 2, nxt2);

    const ushort* kb0 = &sm[curoff];
    const ushort* vb0 = &sm[curoff + 4096];
    // this wave's uu is fixed: uu == jw (partner wave takes the other half)
    bf16x8 kf[2][2], vf[4];
#pragma unroll
    for (int ss = 0; ss < 2; ++ss)
#pragma unroll
      for (int hf = 0; hf < 2; ++hf)
        kf[ss][hf] = *reinterpret_cast<const bf16x8*>(
            kb0 + jw * 2048 + ss * 1024 + hf * 512 + lane * 8);
#pragma unroll
    for (int dt = 0; dt < 4; ++dt)
      vf[dt] = *reinterpret_cast<const bf16x8*>(
          vb0 + dt * 1024 + jw * 512 + lane * 8);

#pragma unroll
    for (int qt2 = 0; qt2 < 2; ++qt2) {
      f32x4 st0 = (f32x4){0.f, 0.f, 0.f, 0.f};
      f32x4 st1 = (f32x4){0.f, 0.f, 0.f, 0.f};
      st0 = mfma32(kf[0][0], qf[qt2][0], st0);
      st0 = mfma32(kf[0][1], qf[qt2][1], st0);
      st1 = mfma32(kf[1][0], qf[qt2][0], st1);
      st1 = mfma32(kf[1][1], qf[qt2][1], st1);
      unsigned b0 = __float_as_uint(fexp2(st0[0]));
      unsigned b1 = __float_as_uint(fexp2(st0[1]));
      unsigned b2 = __float_as_uint(fexp2(st0[2]));
      unsigned b3 = __float_as_uint(fexp2(st0[3]));
      unsigned b4 = __float_as_uint(fexp2(st1[0]));
      unsigned b5 = __float_as_uint(fexp2(st1[1]));
      unsigned b6 = __float_as_uint(fexp2(st1[2]));
      unsigned b7 = __float_as_uint(fexp2(st1[3]));
      // rowsum of TRUNCATED P (matches PV numerator quantization exactly)
      float t0 = __uint_as_float(b0 & 0xffff0000u);
      float t1 = __uint_as_float(b1 & 0xffff0000u);
      float t2 = __uint_as_float(b2 & 0xffff0000u);
      float t3 = __uint_as_float(b3 & 0xffff0000u);
      float t4 = __uint_as_float(b4 & 0xffff0000u);
      float t5 = __uint_as_float(b5 & 0xffff0000u);
      float t6 = __uint_as_float(b6 & 0xffff0000u);
      float t7 = __uint_as_float(b7 & 0xffff0000u);
      rs[qt2] += ((t0 + t1) + (t2 + t3)) + ((t4 + t5) + (t6 + t7));
      union { unsigned u[4]; bf16x8 v; } pk;
      pk.u[0] = __builtin_amdgcn_perm(b1, b0, 0x07060302u);
      pk.u[1] = __builtin_amdgcn_perm(b3, b2, 0x07060302u);
      pk.u[2] = __builtin_amdgcn_perm(b5, b4, 0x07060302u);
      pk.u[3] = __builtin_amdgcn_perm(b7, b6, 0x07060302u);
#pragma unroll
      for (int dt = 0; dt < 4; ++dt)
        oacc[qt2][dt] = mfma32(vf[dt], pk.v, oacc[qt2][dt]);
    }

    cur = cur == 2 ? 0 : cur + 1;
    nxt2 = nxt2 == 2 ? 0 : nxt2 + 1;
  }

  // epilogue: full sync before reusing sm (all loads drained at jt=31)
  __syncthreads();

  // combine jw pair via LDS (lov 16KB at byte 0, lrs 1KB at byte 16384)
  f32x4* lov = reinterpret_cast<f32x4*>(sm);
  float* lrsf = reinterpret_cast<float*>(sm + 8192);   // byte offset 16KB
  if (jw) {
#pragma unroll
    for (int qt2 = 0; qt2 < 2; ++qt2) {
#pragma unroll
      for (int dt = 0; dt < 4; ++dt)
        lov[(qw * 8 + qt2 * 4 + dt) * 64 + lane] = oacc[qt2][dt];
      lrsf[(qw * 2 + qt2) * 64 + lane] = rs[qt2];
    }
  }
  __syncthreads();
  if (!jw) {
#pragma unroll
    for (int qt2 = 0; qt2 < 2; ++qt2) {
      float r = rs[qt2] + lrsf[(qw * 2 + qt2) * 64 + lane];
      r += __shfl_xor(r, 16, 64);
      r += __shfl_xor(r, 32, 64);
      const float inv = 1.0f / r;

      const int mt2 = b * 128 + qt * 4 + qw * 2 + qt2;
#pragma unroll
      for (int dt = 0; dt < 4; ++dt) {
        f32x4 a = oacc[qt2][dt];
        a += lov[(qw * 8 + qt2 * 4 + dt) * 64 + lane];
        unsigned r0 = f2bf(a[0] * inv), r1 = f2bf(a[1] * inv);
        unsigned r2 = f2bf(a[2] * inv), r3 = f2bf(a[3] * inv);
        uint2 ww;
        ww.x = r0 | (r1 << 16);
        ww.y = r2 | (r3 << 16);
        size_t addr = (size_t)(mt2 * 10 + h * 2 + (dt >> 1)) * 512 +
                      ((((dt & 1) * 2 + (quad >> 1)) * 16 + m16)) * 8 +
                      (quad & 1) * 4;
        *reinterpret_cast<uint2*>(ao + addr) = ww;
      }
    }
  }
}

// ---------------------------------------------------------------------------
// Kernel 3: output projection, swapped operands; r11: 4-wave blocks with
// wave = 32m x 64n -> 1280 waves (full SIMD coverage vs 640 before).
// grid 320 flat XCD-swizzled -> (mg 0..63, ct 0..4); block covers 128m.
// ---------------------------------------------------------------------------
__global__ __launch_bounds__(256, 3) void oproj_gemm(
    const ushort* __restrict__ ao, const ushort* __restrict__ wt,
    const float* __restrict__ bo, float* __restrict__ out)
{
  const int w = blockIdx.x;
  const int s = (w & 7) * 40 + (w >> 3);
  const int mg = s / 5, ct = s % 5;
  const int wave = threadIdx.x >> 6, lane = threadIdx.x & 63;
  const int m16 = lane & 15, quad = lane >> 4;
  const int m0 = mg * 128 + wave * 32;
  const int n0 = ct * 64;
  const ushort* atile = ao + (size_t)(m0 >> 4) * 5120 + lane * 8;
  const ushort* btile = wt + (size_t)3 * 102400 + (size_t)(ct * 4) * 5120 + lane * 8;

  f32x4 acc[2][4];
#pragma unroll
  for (int i = 0; i < 2; ++i)
#pragma unroll
    for (int ns = 0; ns < 4; ++ns) acc[i][ns] = (f32x4){0.f, 0.f, 0.f, 0.f};

#pragma unroll
  for (int kc = 0; kc < 10; ++kc) {
    bf16x8 af[2], bf[4];
#pragma unroll
    for (int i = 0; i < 2; ++i)
      af[i] = *reinterpret_cast<const bf16x8*>(atile + (i * 10 + kc) * 512);
#pragma unroll
    for (int ns = 0; ns < 4; ++ns)
      bf[ns] = *reinterpret_cast<const bf16x8*>(btile + (ns * 10 + kc) * 512);
    // swapped: lane holds out-row = m16 within i-tile, 4 consecutive cols
#pragma unroll
    for (int i = 0; i < 2; ++i)
#pragma unroll
      for (int ns = 0; ns < 4; ++ns)
        acc[i][ns] = mfma32(bf[ns], af[i], acc[i][ns]);
  }

  float4 bb[4];
#pragma unroll
  for (int ns = 0; ns < 4; ++ns)
    bb[ns] = *reinterpret_cast<const float4*>(bo + n0 + ns * 16 + quad * 4);
#pragma unroll
  for (int i = 0; i < 2; ++i) {
    const int mrow = m0 + i * 16 + m16;
#pragma unroll
    for (int ns = 0; ns < 4; ++ns) {
      float4 o;
      o.x = acc[i][ns][0] + bb[ns].x;
      o.y = acc[i][ns][1] + bb[ns].y;
      o.z = acc[i][ns][2] + bb[ns].z;
      o.w = acc[i][ns][3] + bb[ns].w;
      *reinterpret_cast<float4*>(
          out + (size_t)mrow * 320 + n0 + ns * 16 + quad * 4) = o;
    }
  }
}

// ---------------------------------------------------------------------------
extern "C" void kernel_launch(void* const* d_in, const int* in_sizes, int n_in,
                              void* d_out, int out_size, void* d_ws, size_t ws_size,
                              hipStream_t stream) {
  const float* x    = (const float*)d_in[0];
  const float* edge = (const float*)d_in[1];
  const float* Wq   = (const float*)d_in[2];
  const float* Wk   = (const float*)d_in[3];
  const float* Wv   = (const float*)d_in[4];
  const float* Wo   = (const float*)d_in[5];
  const float* bo   = (const float*)d_in[6];
  float* out = (float*)d_out;

  ushort* xb = (ushort*)d_ws;                       // 8192*320
  ushort* wt = xb + (size_t)8192 * 320;             // 4*320*320
  ushort* qp = wt + (size_t)4 * 320 * 320;          // 20*2048*64
  ushort* kS = qp + (size_t)20 * 2048 * 64;
  ushort* vS = kS + (size_t)20 * 2048 * 64;
  ushort* ao = vS + (size_t)20 * 2048 * 64;

  prep_kernel<<<3360, 256, 0, stream>>>(x, Wq, Wk, Wv, Wo, xb, wt);
  qkv_gemm<<<480, 256, 0, stream>>>(xb, edge, wt, qp, kS, vS);
  attn_kernel<<<640, 256, 0, stream>>>(qp, kS, vS, ao);
  oproj_gemm<<<320, 256, 0, stream>>>(ao, wt, bo, out);
}

// Round 8
// 124.173 us; speedup vs baseline: 1.1972x; 1.0554x over previous
//
#include <hip/hip_runtime.h>
#include <hip/hip_bf16.h>
#include <math.h>

// B=4, N=2048, C=320, H=5, D=64, INNER=320, BH=20
// logit = (q*0.125*log2e*e_i) . (k*e_j); softmax via exp2 (bounded, no max).
// e_bh = edge[(b+h)%4]  (batch-minor edge tiling vs batch-major heads)
//
// Fragment-major layouts (every main-loop load = lane-contiguous b128):
//  xb  tiles (mt2=m/16, kc=k/32): elem (qq*16+mm)*8+e  = x[m][k], qq=(k%32)>>3
//  wt  tiles (z, nt2=n/16, kc):   elem (qq*16+nn)*8+e  = W[k][n]
//  kS  [bh][j/16][d/32][slot]:    slot ((d>>3)&3)*16+(j&15), e=d&7
//  vS  [bh][d/16][j/64][kb][slot]: PV mfma32 A-frag order (see r3 notes)
//  ao  tiles like xb (A-operand of oproj)
//  qp  row-major [bh][n][64]
//
// r19: back to the measured-best r9 structure (round-0 anchor, 124.3us)
// + T5 s_setprio around attn MFMA clusters. Session findings: five
// schedule variants (flash LDS 2-buf/3-buf, counted vmcnt, jw roles,
// QBLK=64/128) all land attn ~36us vs r9's ~32-35; barrier-drain, LDS
// traffic, and occupancy theories each individually refuted by neutral
// A/Bs. r9's barrier-free register ping-pong at ~3 waves/SIMD is the
// m191 regime where setprio measured +4-7% (independent waves at
// different phases), unlike lockstep GEMM (m190, hurts).
// Ledger: 2 poison fills ~85us (80% HBM peak, harness-fixed) +
// prep/qkv/oproj ~9us + attn ~32us = wall.

typedef short bf16x8 __attribute__((ext_vector_type(8)));
typedef float f32x4 __attribute__((ext_vector_type(4)));

static __device__ __forceinline__ ushort f2bf(float f) {
  union { float f; unsigned u; } v; v.f = f;
  unsigned r = (v.u + 0x7fffu + ((v.u >> 16) & 1u)) >> 16;
  return (ushort)r;
}
static __device__ __forceinline__ float fexp2(float x) {
#if __has_builtin(__builtin_amdgcn_exp2f)
  return __builtin_amdgcn_exp2f(x);
#else
  return exp2f(x);
#endif
}
static __device__ __forceinline__ f32x4 mfma32(bf16x8 a, bf16x8 b, f32x4 c) {
  return __builtin_amdgcn_mfma_f32_16x16x32_bf16(a, b, c, 0, 0, 0);
}

// ---------------------------------------------------------------------------
// Prep (fused): flat grid 3360. (verbatim r9)
// ---------------------------------------------------------------------------
__global__ __launch_bounds__(256) void prep_kernel(
    const float* __restrict__ x,
    const float* __restrict__ Wq, const float* __restrict__ Wk,
    const float* __restrict__ Wv, const float* __restrict__ Wo,
    ushort* __restrict__ xb, ushort* __restrict__ wt)
{
  const int w = blockIdx.x;
  if (w < 2560) {
    const int t = threadIdx.x;
    const int mt2 = w / 5;
    const int kc = (w % 5) * 2 + (t >> 7);
    const int f = (t & 127) * 4;
    const int qq = f >> 7, mm = (f >> 3) & 15, e0 = f & 7;
    float4 v = *reinterpret_cast<const float4*>(
        x + (size_t)(mt2 * 16 + mm) * 320 + kc * 32 + qq * 8 + e0);
    ushort4 o = { f2bf(v.x), f2bf(v.y), f2bf(v.z), f2bf(v.w) };
    *reinterpret_cast<ushort4*>(xb + (size_t)(mt2 * 10 + kc) * 512 + f) = o;
  } else {
    const int w2 = w - 2560;
    const int nt2 = w2 % 20, kc = (w2 / 20) % 10, z = w2 / 200;
    const float* W = z == 0 ? Wq : z == 1 ? Wk : z == 2 ? Wv : Wo;
    const int f = threadIdx.x * 2;
    const int qq = f >> 7, nn = (f >> 3) & 15, e0 = f & 7;
    const int k = kc * 32 + qq * 8 + e0, n = nt2 * 16 + nn;
    float v0 = W[(size_t)k * 320 + n];
    float v1 = W[(size_t)(k + 1) * 320 + n];
    ushort2 o = { f2bf(v0), f2bf(v1) };
    *reinterpret_cast<ushort2*>(
        wt + (size_t)z * 102400 + (size_t)(nt2 * 10 + kc) * 512 + f) = o;
  }
}

// ---------------------------------------------------------------------------
// Kernel 1: QKV projection big-tile (verbatim r9).
// ---------------------------------------------------------------------------
__global__ __launch_bounds__(256, 3) void qkv_gemm(
    const ushort* __restrict__ xb, const float* __restrict__ edge,
    const ushort* __restrict__ wt,
    ushort* __restrict__ qp, ushort* __restrict__ kS, ushort* __restrict__ vS)
{
  const int w = blockIdx.x;
  const int s = (w & 7) * 60 + (w >> 3);
  const int mg = s / 15, zh = s % 15;
  const int z = zh / 5, h = zh % 5;
  const int wave = threadIdx.x >> 6, lane = threadIdx.x & 63;
  const int m16 = lane & 15, quad = lane >> 4;
  const int m0 = mg * 256 + wave * 64;
  const ushort* atile = xb + (size_t)(m0 >> 4) * 5120 + lane * 8;
  const ushort* btile = wt + (size_t)z * 102400 + (size_t)(h * 4) * 5120 + lane * 8;

  f32x4 acc[4][4];
#pragma unroll
  for (int i = 0; i < 4; ++i)
#pragma unroll
    for (int ns = 0; ns < 4; ++ns) acc[i][ns] = (f32x4){0.f, 0.f, 0.f, 0.f};

#pragma unroll
  for (int kc = 0; kc < 10; ++kc) {
    bf16x8 af[4], bf[4];
#pragma unroll
    for (int i = 0; i < 4; ++i)
      af[i] = *reinterpret_cast<const bf16x8*>(atile + (i * 10 + kc) * 512);
#pragma unroll
    for (int ns = 0; ns < 4; ++ns)
      bf[ns] = *reinterpret_cast<const bf16x8*>(btile + (ns * 10 + kc) * 512);
    if (z == 2) {
#pragma unroll
      for (int i = 0; i < 4; ++i)
#pragma unroll
        for (int ns = 0; ns < 4; ++ns)
          acc[i][ns] = mfma32(af[i], bf[ns], acc[i][ns]);
    } else {
#pragma unroll
      for (int i = 0; i < 4; ++i)
#pragma unroll
        for (int ns = 0; ns < 4; ++ns)
          acc[i][ns] = mfma32(bf[ns], af[i], acc[i][ns]);
    }
  }

  const float QSCALE = 0.18033688011112042f;  // 0.125 * log2(e)
  const int b = m0 >> 11;
  const int bh = b * 5 + h;
  const float* eb = edge + (size_t)((b + h) & 3) * 2048;
  const int nwb = m0 & 2047;

  if (z == 0) {
#pragma unroll
    for (int i = 0; i < 4; ++i) {
      const int n = nwb + i * 16 + m16;
      const float e = eb[n] * QSCALE;
      ushort* dst = qp + ((size_t)bh * 2048 + n) * 64 + quad * 4;
#pragma unroll
      for (int ns = 0; ns < 4; ++ns) {
        ushort4 o = { f2bf(acc[i][ns][0] * e), f2bf(acc[i][ns][1] * e),
                      f2bf(acc[i][ns][2] * e), f2bf(acc[i][ns][3] * e) };
        *reinterpret_cast<ushort4*>(dst + ns * 16) = o;
      }
    }
  } else if (z == 1) {
#pragma unroll
    for (int i = 0; i < 4; ++i) {
      const int j = nwb + i * 16 + m16;
      const float e = eb[j];
      const size_t base = (size_t)bh * 131072 +
                          (size_t)((m0 >> 4) + i & 127) * 1024;
#pragma unroll
      for (int ns = 0; ns < 4; ++ns) {
        size_t a0 = base + (ns >> 1) * 512 +
                    ((((ns * 2 + (quad >> 1)) & 3) * 16 + m16)) * 8 +
                    (quad & 1) * 4;
        ushort4 o = { f2bf(acc[i][ns][0] * e), f2bf(acc[i][ns][1] * e),
                      f2bf(acc[i][ns][2] * e), f2bf(acc[i][ns][3] * e) };
        *reinterpret_cast<ushort4*>(kS + a0) = o;
      }
    }
  } else {
    const int jb = nwb >> 6;
#pragma unroll
    for (int i = 0; i < 4; ++i) {
      const int kb = i >> 1, e4 = (i & 1) * 4;
#pragma unroll
      for (int ns = 0; ns < 4; ++ns) {
        ushort4 o = { f2bf(acc[i][ns][0]), f2bf(acc[i][ns][1]),
                      f2bf(acc[i][ns][2]), f2bf(acc[i][ns][3]) };
        size_t addr = (size_t)bh * 131072 + (size_t)ns * 32768 +
                      (size_t)jb * 1024 + kb * 512 +
                      (quad * 16 + m16) * 8 + e4;
        *reinterpret_cast<ushort4*>(vS + addr) = o;
      }
    }
  }
}

// ---------------------------------------------------------------------------
// Kernel 2: attention (r9 structure — best measured). 32q blocks, grid 1280
// flat XCD-swizzled; 4 waves j-split; register Q; K/V ping-pong prefetch
// forced with sched_barrier(0); 3 waves/SIMD. r19: s_setprio(1) around the
// two MFMA clusters (QK; rowsum+PV) — T5, matches the m191 free-running
// multi-wave regime (no barriers in main loop).
// ---------------------------------------------------------------------------
__global__ __launch_bounds__(256, 3) void attn_kernel(
    const ushort* __restrict__ qp, const ushort* __restrict__ kS,
    const ushort* __restrict__ vS, ushort* __restrict__ ao)
{
  __shared__ f32x4 lo[3][8][64];   // 24 KB cross-wave partials
  __shared__ float lrs[4][2][16];
  const int w = blockIdx.x;
  const int s = (w & 7) * 160 + (w >> 3);
  const int bh = s >> 6, qt = s & 63;
  const int b = bh / 5, h = bh % 5;
  const int wave = threadIdx.x >> 6, lane = threadIdx.x & 63;
  const int m16 = lane & 15, quad = lane >> 4;
  const int q0 = qt * 32;

  bf16x8 qf[2][2];
#pragma unroll
  for (int qs = 0; qs < 2; ++qs) {
    const ushort* qrow = qp + ((size_t)bh * 2048 + q0 + qs * 16 + m16) * 64;
    qf[qs][0] = *reinterpret_cast<const bf16x8*>(qrow + quad * 8);
    qf[qs][1] = *reinterpret_cast<const bf16x8*>(qrow + 32 + quad * 8);
  }
  const ushort* kb_p = kS + (size_t)bh * 131072 + lane * 8;
  const ushort* vb_p = vS + (size_t)bh * 131072 + lane * 8;

  f32x4 oacc[2][4], rsacc[2];
#pragma unroll
  for (int qs = 0; qs < 2; ++qs) {
    rsacc[qs] = (f32x4){0.f, 0.f, 0.f, 0.f};
    for (int dt = 0; dt < 4; ++dt) oacc[qs][dt] = (f32x4){0.f, 0.f, 0.f, 0.f};
  }
  const bf16x8 ones8 = {(short)16256, (short)16256, (short)16256, (short)16256,
                        (short)16256, (short)16256, (short)16256, (short)16256};

  auto load_unit = [&](int u, bf16x8 kf[2][2], bf16x8 vf[4]) {
    const int jb = (u >> 1) * 4 + wave, kb = u & 1;
#pragma unroll
    for (int ss = 0; ss < 2; ++ss)
#pragma unroll
      for (int hf = 0; hf < 2; ++hf)
        kf[ss][hf] = *reinterpret_cast<const bf16x8*>(
            kb_p + (size_t)(jb * 4 + kb * 2 + ss) * 1024 + hf * 512);
#pragma unroll
    for (int dt = 0; dt < 4; ++dt)
      vf[dt] = *reinterpret_cast<const bf16x8*>(
          vb_p + (size_t)dt * 32768 + (size_t)jb * 1024 + kb * 512);
  };
  auto compute_unit = [&](bf16x8 kf[2][2], bf16x8 vf[4]) {
#pragma unroll
    for (int qs = 0; qs < 2; ++qs) {
      f32x4 st0 = (f32x4){0.f, 0.f, 0.f, 0.f};
      f32x4 st1 = (f32x4){0.f, 0.f, 0.f, 0.f};
      __builtin_amdgcn_s_setprio(1);
      st0 = mfma32(kf[0][0], qf[qs][0], st0);
      st0 = mfma32(kf[0][1], qf[qs][1], st0);
      st1 = mfma32(kf[1][0], qf[qs][0], st1);
      st1 = mfma32(kf[1][1], qf[qs][1], st1);
      __builtin_amdgcn_s_setprio(0);
      unsigned b0 = __float_as_uint(fexp2(st0[0]));
      unsigned b1 = __float_as_uint(fexp2(st0[1]));
      unsigned b2 = __float_as_uint(fexp2(st0[2]));
      unsigned b3 = __float_as_uint(fexp2(st0[3]));
      unsigned b4 = __float_as_uint(fexp2(st1[0]));
      unsigned b5 = __float_as_uint(fexp2(st1[1]));
      unsigned b6 = __float_as_uint(fexp2(st1[2]));
      unsigned b7 = __float_as_uint(fexp2(st1[3]));
      union { unsigned u[4]; bf16x8 v; } pk;
      pk.u[0] = __builtin_amdgcn_perm(b1, b0, 0x07060302u);
      pk.u[1] = __builtin_amdgcn_perm(b3, b2, 0x07060302u);
      pk.u[2] = __builtin_amdgcn_perm(b5, b4, 0x07060302u);
      pk.u[3] = __builtin_amdgcn_perm(b7, b6, 0x07060302u);
      __builtin_amdgcn_s_setprio(1);
      rsacc[qs] = mfma32(ones8, pk.v, rsacc[qs]);
#pragma unroll
      for (int dt = 0; dt < 4; ++dt)
        oacc[qs][dt] = mfma32(vf[dt], pk.v, oacc[qs][dt]);
      __builtin_amdgcn_s_setprio(0);
    }
  };

  bf16x8 kA[2][2], vA[4], kB[2][2], vB[4];
  load_unit(0, kA, vA);
  __builtin_amdgcn_sched_barrier(0);
#pragma unroll
  for (int u = 0; u < 16; u += 2) {
    load_unit(u + 1, kB, vB);
    __builtin_amdgcn_sched_barrier(0);
    compute_unit(kA, vA);
    if (u + 2 < 16) load_unit(u + 2, kA, vA);
    __builtin_amdgcn_sched_barrier(0);
    compute_unit(kB, vB);
    __builtin_amdgcn_sched_barrier(0);
  }

  if (wave > 0) {
#pragma unroll
    for (int qs = 0; qs < 2; ++qs)
#pragma unroll
      for (int dt = 0; dt < 4; ++dt)
        lo[wave - 1][qs * 4 + dt][lane] = oacc[qs][dt];
  }
  if (quad == 0) {
    lrs[wave][0][m16] = rsacc[0][0];
    lrs[wave][1][m16] = rsacc[1][0];
  }
  __syncthreads();
  if (wave == 0) {
#pragma unroll
    for (int qs = 0; qs < 2; ++qs) {
      float inv = 1.0f / (lrs[0][qs][m16] + lrs[1][qs][m16] +
                          lrs[2][qs][m16] + lrs[3][qs][m16]);
      const int mt2 = b * 128 + qt * 2 + qs;
#pragma unroll
      for (int dt = 0; dt < 4; ++dt) {
        f32x4 a = oacc[qs][dt];
        a += lo[0][qs * 4 + dt][lane];
        a += lo[1][qs * 4 + dt][lane];
        a += lo[2][qs * 4 + dt][lane];
        unsigned r0 = f2bf(a[0] * inv), r1 = f2bf(a[1] * inv);
        unsigned r2 = f2bf(a[2] * inv), r3 = f2bf(a[3] * inv);
        uint2 ww;
        ww.x = r0 | (r1 << 16);
        ww.y = r2 | (r3 << 16);
        size_t addr = (size_t)(mt2 * 10 + h * 2 + (dt >> 1)) * 512 +
                      ((((dt & 1) * 2 + (quad >> 1)) * 16 + m16)) * 8 +
                      (quad & 1) * 4;
        *reinterpret_cast<uint2*>(ao + addr) = ww;
      }
    }
  }
}

// ---------------------------------------------------------------------------
// Kernel 3: output projection, swapped operands; 4-wave blocks with
// wave = 32m x 64n -> 1280 waves; grid 320 flat XCD-swizzled.
// ---------------------------------------------------------------------------
__global__ __launch_bounds__(256, 3) void oproj_gemm(
    const ushort* __restrict__ ao, const ushort* __restrict__ wt,
    const float* __restrict__ bo, float* __restrict__ out)
{
  const int w = blockIdx.x;
  const int s = (w & 7) * 40 + (w >> 3);
  const int mg = s / 5, ct = s % 5;
  const int wave = threadIdx.x >> 6, lane = threadIdx.x & 63;
  const int m16 = lane & 15, quad = lane >> 4;
  const int m0 = mg * 128 + wave * 32;
  const int n0 = ct * 64;
  const ushort* atile = ao + (size_t)(m0 >> 4) * 5120 + lane * 8;
  const ushort* btile = wt + (size_t)3 * 102400 + (size_t)(ct * 4) * 5120 + lane * 8;

  f32x4 acc[2][4];
#pragma unroll
  for (int i = 0; i < 2; ++i)
#pragma unroll
    for (int ns = 0; ns < 4; ++ns) acc[i][ns] = (f32x4){0.f, 0.f, 0.f, 0.f};

#pragma unroll
  for (int kc = 0; kc < 10; ++kc) {
    bf16x8 af[2], bf[4];
#pragma unroll
    for (int i = 0; i < 2; ++i)
      af[i] = *reinterpret_cast<const bf16x8*>(atile + (i * 10 + kc) * 512);
#pragma unroll
    for (int ns = 0; ns < 4; ++ns)
      bf[ns] = *reinterpret_cast<const bf16x8*>(btile + (ns * 10 + kc) * 512);
    // swapped: lane holds out-row = m16 within i-tile, 4 consecutive cols
#pragma unroll
    for (int i = 0; i < 2; ++i)
#pragma unroll
      for (int ns = 0; ns < 4; ++ns)
        acc[i][ns] = mfma32(bf[ns], af[i], acc[i][ns]);
  }

  float4 bb[4];
#pragma unroll
  for (int ns = 0; ns < 4; ++ns)
    bb[ns] = *reinterpret_cast<const float4*>(bo + n0 + ns * 16 + quad * 4);
#pragma unroll
  for (int i = 0; i < 2; ++i) {
    const int mrow = m0 + i * 16 + m16;
#pragma unroll
    for (int ns = 0; ns < 4; ++ns) {
      float4 o;
      o.x = acc[i][ns][0] + bb[ns].x;
      o.y = acc[i][ns][1] + bb[ns].y;
      o.z = acc[i][ns][2] + bb[ns].z;
      o.w = acc[i][ns][3] + bb[ns].w;
      *reinterpret_cast<float4*>(
          out + (size_t)mrow * 320 + n0 + ns * 16 + quad * 4) = o;
    }
  }
}

// ---------------------------------------------------------------------------
extern "C" void kernel_launch(void* const* d_in, const int* in_sizes, int n_in,
                              void* d_out, int out_size, void* d_ws, size_t ws_size,
                              hipStream_t stream) {
  const float* x    = (const float*)d_in[0];
  const float* edge = (const float*)d_in[1];
  const float* Wq   = (const float*)d_in[2];
  const float* Wk   = (const float*)d_in[3];
  const float* Wv   = (const float*)d_in[4];
  const float* Wo   = (const float*)d_in[5];
  const float* bo   = (const float*)d_in[6];
  float* out = (float*)d_out;

  ushort* xb = (ushort*)d_ws;                       // 8192*320
  ushort* wt = xb + (size_t)8192 * 320;             // 4*320*320
  ushort* qp = wt + (size_t)4 * 320 * 320;          // 20*2048*64
  ushort* kS = qp + (size_t)20 * 2048 * 64;
  ushort* vS = kS + (size_t)20 * 2048 * 64;
  ushort* ao = vS + (size_t)20 * 2048 * 64;

  prep_kernel<<<3360, 256, 0, stream>>>(x, Wq, Wk, Wv, Wo, xb, wt);
  qkv_gemm<<<480, 256, 0, stream>>>(xb, edge, wt, qp, kS, vS);
  attn_kernel<<<1280, 256, 0, stream>>>(qp, kS, vS, ao);
  oproj_gemm<<<320, 256, 0, stream>>>(ao, wt, bo, out);
}